// Round 10
// baseline (216.983 us; speedup 1.0000x reference)
//
#include <hip/hip_runtime.h>

// CrossWinAttention on MI355X (gfx950), bf16 MFMA pipeline. R15:
//  - R14 closed in-kernel MLP (depth-12 prefetch null; 9th falsification of
//    a per-wave lever at k_attn ~52-55us). Remaining measured lever: R13's
//    concurrency result (24 waves/CU -> 600 GB/s sustained) was self-defeated
//    by FETCH 18.5->30.8 MB: the two n-halves of each (bl,h) pair fetch the
//    SAME 49 KB of K/V but land on different XCDs (round-robin dispatch), so
//    the duplicate misses the private L2.
//  - R15 = R13b + pair-wise XCD affinity: wgid = g*512 + p (512 = 0 mod 8 ->
//    both halves of pair p share wgid mod 8 -> same XCD -> duplicate K/V
//    fetch hits shared L2). Per-XCD unique K/V = 64 pairs x 49 KB = 3.1 MB
//    < 4 MB L2. All 1024 blocks co-resident (33.3KB LDS x4 = 133 < 160KB,
//    12 waves/CU, VGPR ~84) so pairs run temporally aligned.
//  - k_prep (grid 16) / k_lnproj (LDS-staged stores) / k_out (f32-partial
//    sum): R13b versions, verified passing.
//  - Carried: S^T trick, V^T key-swizzle, LN folded into GEMM epilogue,
//    mean-over-N folded, scale*log2e folded into wq/bq (exp2-only softmax),
//    serial-sle softmax (best-measured), hw bf16 cvt.

typedef unsigned short u16;
typedef __bf16 bf16x8 __attribute__((ext_vector_type(8)));
typedef __bf16 bf16x4 __attribute__((ext_vector_type(4)));
typedef float  f32x16 __attribute__((ext_vector_type(16)));
typedef unsigned short u16x8 __attribute__((ext_vector_type(8)));
typedef unsigned short u16x4 __attribute__((ext_vector_type(4)));

union U8 { u16x8 u; bf16x8 b; u16x4 h[2]; };

#if __has_builtin(__builtin_amdgcn_exp2f)
#define EXP2(x) __builtin_amdgcn_exp2f(x)
#else
#define EXP2(x) exp2f(x)
#endif

__device__ __forceinline__ f32x16 mfma_bf16(bf16x8 a, bf16x8 b, f32x16 c){
  return __builtin_amdgcn_mfma_f32_32x32x16_bf16(a, b, c, 0, 0, 0);
}

// 32x32x16 bf16 fragment conventions:
//  A: m=lane&31, k=(lane>>5)*8+j ; B: n=lane&31, k=(lane>>5)*8+j
//  C/D: col=lane&31, row=(reg&3)+8*(reg>>2)+4*(lane>>5)   [verified m74/m101]
// S^T = mfma(K, Q): col = q (fixed per lane), reg axis = keys. V^T stored with
// matching key swizzle so PV B-fragments are single 16B reads.

// ---------------------------------------------------------------- k_prep
// grid 16 = 4 weights x 4 col-chunks; 512 thr.
__global__ __launch_bounds__(512) void k_prep(
    const float* __restrict__ wq, const float* __restrict__ bq,
    const float* __restrict__ gq, const float* __restrict__ betq,
    const float* __restrict__ wk, const float* __restrict__ bk,
    const float* __restrict__ gk, const float* __restrict__ betk,
    const float* __restrict__ wv, const float* __restrict__ bv,
    const float* __restrict__ gv, const float* __restrict__ betv,
    const float* __restrict__ wp,
    u16* __restrict__ wqT, u16* __restrict__ wkT, u16* __restrict__ wvT, u16* __restrict__ wpT,
    float* __restrict__ bq2, float* __restrict__ bk2, float* __restrict__ bv2,
    float* __restrict__ uq2, float* __restrict__ uk2, float* __restrict__ uv2)
{
  __shared__ float wls[128*33];
  __shared__ float gls[128], bls[128];
  __shared__ float redb[128], redu[128];
  const float ALPHA_Q = 0.17677669529663687f * 1.4426950408889634f; // DH^-0.5 * log2(e)
  int bid = blockIdx.x, tid = threadIdx.x;
  int wsel = bid >> 2, chunk = bid & 3;
  const float *w, *bb, *g, *bet; u16* wT; float *b2, *u2; float alpha;
  if (wsel == 0){ w=wq; bb=bq; g=gq; bet=betq; wT=wqT; b2=bq2; u2=uq2; alpha=ALPHA_Q; }
  else if (wsel == 1){ w=wk; bb=bk; g=gk; bet=betk; wT=wkT; b2=bk2; u2=uk2; alpha=1.f; }
  else if (wsel == 2){ w=wv; bb=bv; g=gv; bet=betv; wT=wvT; b2=bv2; u2=uv2; alpha=1.f; }
  else { w=wp; bb=nullptr; g=nullptr; bet=nullptr; wT=wpT; b2=nullptr; u2=nullptr; alpha=1.f; }

  if (tid < 128){
    gls[tid] = g ? g[tid] : 1.f;
    bls[tid] = bet ? bet[tid] : 0.f;
  }
  const float4* w4 = (const float4*)w;
  #pragma unroll
  for (int i = 0; i < 2; i++){
    int idx = tid + i*512;
    int row = idx >> 3, f4c = idx & 7;
    float4 x = w4[row*32 + chunk*8 + f4c];
    wls[row*33 + f4c*4 + 0] = x.x;
    wls[row*33 + f4c*4 + 1] = x.y;
    wls[row*33 + f4c*4 + 2] = x.z;
    wls[row*33 + f4c*4 + 3] = x.w;
  }
  __syncthreads();
  if (tid < 128){
    int nl = tid >> 2, qp = tid & 3;
    float sb = 0.f, su = 0.f;
    alignas(16) __bf16 tmp[32];
    #pragma unroll
    for (int kk = 0; kk < 32; kk++){
      int k2 = qp*32 + kk;
      float wv_ = wls[k2*33 + nl];
      float gv_ = gls[k2];
      sb += bls[k2] * wv_;
      su += gv_ * wv_;
      tmp[kk] = (__bf16)(wv_ * gv_ * alpha);
    }
    int n = chunk*32 + nl;
    #pragma unroll
    for (int j = 0; j < 4; j++)
      *(bf16x8*)(wT + n*128 + qp*32 + j*8) = *(bf16x8*)&tmp[j*8];
    redb[tid] = sb; redu[tid] = su;
  }
  __syncthreads();
  if (tid < 128){
    int nl = tid >> 2, qp = tid & 3;
    if (qp == 0 && bb){
      int n = chunk*32 + nl;
      float s = bb[n] + redb[tid] + redb[tid+1] + redb[tid+2] + redb[tid+3];
      float u = redu[tid] + redu[tid+1] + redu[tid+2] + redu[tid+3];
      b2[n] = s * alpha;
      u2[n] = u * alpha;
    }
  }
}

// ---------------------------------------------------------------- k_lnproj
// grid 2304 = 128 (b,l) * 6 (n) * 3 (q/k/v); 256 thr (4 waves).
// Raw-x bf16 GEMM; LN in epilogue; C staged via LDS for coalesced stores.
__global__ __launch_bounds__(256) void k_lnproj(
    const float* __restrict__ qg, const float* __restrict__ kg, const float* __restrict__ vg,
    const u16* __restrict__ wqT, const u16* __restrict__ wkT, const u16* __restrict__ wvT,
    const float* __restrict__ bq2, const float* __restrict__ bk2, const float* __restrict__ bv2,
    const float* __restrict__ uq2, const float* __restrict__ uk2, const float* __restrict__ uv2,
    u16* __restrict__ qh, u16* __restrict__ kh, u16* __restrict__ vh)
{
  __shared__ alignas(16) u16 Abf[64*136];
  __shared__ float s1s[64], s2s[64];     // rs / rm
  int bid = blockIdx.x, tid = threadIdx.x;
  int which = bid % 3;
  int t = bid / 3;
  int n = t % 6, bl = t / 6;
  const float* src; const u16* wT; const float *b2, *u2; u16* dstb;
  if (which == 0){ src=qg; wT=wqT; b2=bq2; u2=uq2; dstb=qh; }
  else if (which == 1){ src=kg; wT=wkT; b2=bk2; u2=uk2; dstb=kh; }
  else { src=vg; wT=wvT; b2=bv2; u2=uv2; dstb=vh; }
  int b = bl >> 6, l = bl & 63;
  const float4* s4 = (const float4*)(src + (size_t)((b*6 + n)*64 + l)*64*128);
  int row = tid >> 2, j = tid & 3;
  float s1 = 0.f, s2 = 0.f;
  #pragma unroll
  for (int i = 0; i < 8; i++){
    float4 xv = s4[row*32 + i*4 + j];
    s1 += xv.x + xv.y + xv.z + xv.w;
    s2 += xv.x*xv.x + xv.y*xv.y + xv.z*xv.z + xv.w*xv.w;
    bf16x4 pk;
    pk[0] = (__bf16)xv.x; pk[1] = (__bf16)xv.y;
    pk[2] = (__bf16)xv.z; pk[3] = (__bf16)xv.w;
    *(bf16x4*)&Abf[row*136 + (i*4 + j)*4] = pk;
  }
  s1 += __shfl_xor(s1, 1, 64); s1 += __shfl_xor(s1, 2, 64);
  s2 += __shfl_xor(s2, 1, 64); s2 += __shfl_xor(s2, 2, 64);
  if (j == 0){
    float m = s1 * (1.f/128.f);
    float r = rsqrtf(s2 * (1.f/128.f) - m*m + 1e-5f);
    s1s[row] = r;          // rs
    s2s[row] = r * m;      // rm
  }
  __syncthreads();
  int wave = tid >> 6, lane = tid & 63, lm = lane & 31, lh = lane >> 5;
  bf16x8 bfr[8];
  const u16* wrow = wT + (32*wave + lm)*128 + lh*8;
  #pragma unroll
  for (int ks = 0; ks < 8; ks++) bfr[ks] = *(const bf16x8*)(wrow + ks*16);
  f32x16 acc0, acc1;
  #pragma unroll
  for (int r = 0; r < 16; r++){ acc0[r]=0.f; acc1[r]=0.f; }
  #pragma unroll
  for (int ks = 0; ks < 8; ks++){
    bf16x8 a0 = *(const bf16x8*)&Abf[lm*136       + ks*16 + lh*8];
    bf16x8 a1 = *(const bf16x8*)&Abf[(32+lm)*136  + ks*16 + lh*8];
    acc0 = mfma_bf16(a0, bfr[ks], acc0);
    acc1 = mfma_bf16(a1, bfr[ks], acc1);
  }
  int col = 32*wave + lm;
  float u2c = u2[col], bc = b2[col];
  __syncthreads();                       // all waves done READING Abf
  #pragma unroll
  for (int r = 0; r < 16; r++){
    int row0 = (r&3) + 8*(r>>2) + 4*lh;
    float y0 = s1s[row0]     * acc0[r] - s2s[row0]     * u2c + bc;
    float y1 = s1s[row0+32]  * acc1[r] - s2s[row0+32]  * u2c + bc;
    *(__bf16*)&Abf[row0*136 + col]      = (__bf16)y0;
    *(__bf16*)&Abf[(32+row0)*136 + col] = (__bf16)y1;
  }
  __syncthreads();
  // coalesced store: 1024 u16x8 chunks = 4 colgroups x 64 rows x 4 parts
  #pragma unroll
  for (int i = 0; i < 4; i++){
    int c = tid + i*256;
    int grp = c >> 8, rw = (c >> 2) & 63, part = c & 3;
    u16x8 val = *(const u16x8*)&Abf[rw*136 + grp*32 + part*8];
    *(u16x8*)(dstb + ((size_t)(bl*4 + grp)*384 + n*64 + rw)*32 + part*8) = val;
  }
}

// ---------------------------------------------------------------- k_attn
// grid 1024; wgid = g*512 + p: p = (bl,h) pair 0..511, g = n-half 0..1.
// 512 = 0 mod 8 -> both halves of pair p share wgid%8 -> same XCD under
// round-robin dispatch -> the duplicated K/V fetch hits the shared L2
// (per-XCD unique K/V = 64 pairs x 49 KB = 3.1 MB < 4 MB L2).
// 192 thr = 3 waves; wave = n within half. LDS 33.3 KB -> 4 blocks/CU =
// 12 waves/CU. f32 partial output per half; k_out sums.
__global__ __launch_bounds__(192) void k_attn(
    const u16* __restrict__ qh, const u16* __restrict__ kh, const u16* __restrict__ vh,
    float* __restrict__ abp0, float* __restrict__ abp1)
{
  __shared__ alignas(16) u16 vts[32*392];   // V^T [dh][swizzled key], stride 392
  __shared__ float abar_s[64*32];
  int bid = blockIdx.x, tid = threadIdx.x;
  int g = bid >> 9;                   // n-half: n in {3g,3g+1,3g+2}
  int bh = bid & 511;                 // (bl,h) pair index
  int h = bh & 3, bl = bh >> 2;
  const u16* qb = qh + (size_t)bh * 12288;
  const u16* kb = kh + (size_t)bh * 12288;
  const u16* vb = vh + (size_t)bh * 12288;

  int wave = tid >> 6, lane = tid & 63, lm = lane & 31, lh = lane >> 5;
  int n = g*3 + wave;

  // Q fragments: group A = q rows n*64+lm, group B = +32
  const u16* qbase = qb + (size_t)(n*64 + lm)*32 + lh*8;
  bf16x8 qfA0 = *(const bf16x8*)(qbase);
  bf16x8 qfA1 = *(const bf16x8*)(qbase + 16);
  bf16x8 qfB0 = *(const bf16x8*)(qbase + 32*32);
  bf16x8 qfB1 = *(const bf16x8*)(qbase + 32*32 + 16);

  // stage V transposed + key-swizzled: a-group perm {0,2,1,3,4,6,5,7}
  #pragma unroll
  for (int i = 0; i < 8; i++){
    int c = tid + i*192;               // 1536 16B chunks
    int key = c >> 2, part = c & 3;
    int u = key & 31, tt = key >> 5;
    int a = u >> 2;
    int anew = (a & 4) | ((a & 1) << 1) | ((a >> 1) & 1);
    int pos = tt*32 + anew*4 + (u & 3);
    u16x8 vv = *(const u16x8*)(vb + key*32 + part*8);
    #pragma unroll
    for (int jj = 0; jj < 8; jj++) vts[(part*8 + jj)*392 + pos] = vv[jj];
  }
  for (int idx = tid; idx < 2048; idx += 192) abar_s[idx] = 0.f;
  __syncthreads();

  const u16* vrow = &vts[lm*392 + 8*lh];
  const u16* krow = kb + lm*32 + lh*8;

  f32x16 oA, oB;
  #pragma unroll
  for (int r = 0; r < 16; r++){ oA[r]=0.f; oB[r]=0.f; }
  float sleA = 0.f, sleB = 0.f;

  #pragma unroll
  for (int kt = 0; kt < 12; kt++){
    bf16x8 kf0 = *(const bf16x8*)(krow + kt*1024);
    bf16x8 kf1 = *(const bf16x8*)(krow + kt*1024 + 16);
    f32x16 sa, sb_;
    #pragma unroll
    for (int r = 0; r < 16; r++){ sa[r] = 0.f; sb_[r] = 0.f; }
    __builtin_amdgcn_s_setprio(1);
    sa  = mfma_bf16(kf0, qfA0, sa);      // two independent chains (A/B)
    sb_ = mfma_bf16(kf0, qfB0, sb_);
    sa  = mfma_bf16(kf1, qfA1, sa);
    sb_ = mfma_bf16(kf1, qfB1, sb_);
    __builtin_amdgcn_s_setprio(0);
    U8 v0, v1;
    v0.u = *(const u16x8*)(vrow + kt*32);
    v1.u = *(const u16x8*)(vrow + kt*32 + 16);
    U8 pA0, pA1, pB0, pB1;
    #pragma unroll
    for (int r = 0; r < 8; r++){
      float eA0 = EXP2(sa[r]);
      float eA1 = EXP2(sa[r+8]);
      float eB0 = EXP2(sb_[r]);
      float eB1 = EXP2(sb_[r+8]);
      sleA += eA0 + eA1;
      sleB += eB0 + eB1;
      pA0.b[r] = (__bf16)eA0;            // v_cvt_pk_bf16_f32 (RNE)
      pA1.b[r] = (__bf16)eA1;
      pB0.b[r] = (__bf16)eB0;
      pB1.b[r] = (__bf16)eB1;
    }
    __builtin_amdgcn_s_setprio(1);
    oA = mfma_bf16(pA0.b, v0.b, oA);
    oB = mfma_bf16(pB0.b, v0.b, oB);
    oA = mfma_bf16(pA1.b, v1.b, oA);
    oB = mfma_bf16(pB1.b, v1.b, oB);
    __builtin_amdgcn_s_setprio(0);
  }

  // row sums: combine lh halves, broadcast reciprocals (1/6 = mean over n)
  sleA += __shfl_xor(sleA, 32, 64);
  sleB += __shfl_xor(sleB, 32, 64);
  float invA = (1.f/6.f) / sleA;
  float invB = (1.f/6.f) / sleB;

  // o lane(lm,lh) reg r = O[q = (r&3)+8*(r>>2)+4*lh][dh = lm]; w12 = q (A), 32+q (B)
  #pragma unroll
  for (int r = 0; r < 16; r++){
    int q_l = (r&3) + 8*(r>>2) + 4*lh;
    float a = oA[r] * __shfl(invA, q_l, 64);
    float b = oB[r] * __shfl(invB, q_l, 64);
    atomicAdd(&abar_s[q_l*32 + lm], a);
    atomicAdd(&abar_s[(32 + q_l)*32 + lm], b);
  }
  __syncthreads();
  float* ob = (g ? abp1 : abp0) + (size_t)(bl*64)*128 + h*32;
  for (int idx = tid; idx < 2048; idx += 192){
    int w12 = idx >> 5, dh = idx & 31;
    ob[(size_t)w12*128 + dh] = abar_s[idx];
  }
}

// ---------------------------------------------------------------- k_out
// grid 256 = 8192 rows / 32; 256 thr (4 waves). Sums the two f32 partials,
// converts once to bf16 in LDS, then GEMM + skip.
__global__ __launch_bounds__(256) void k_out(
    const float* __restrict__ abp0, const float* __restrict__ abp1,
    const u16* __restrict__ wpT,
    const float* __restrict__ bp, const float* __restrict__ skip,
    float* __restrict__ out)
{
  __shared__ alignas(16) u16 Als[32*136];
  int tid = threadIdx.x;
  int R0 = blockIdx.x * 32;
  #pragma unroll
  for (int i = 0; i < 4; i++){
    int c = tid + i*256;                 // 1024 float4 chunks: 32 rows x 32
    int rw = c >> 5, part = c & 31;
    float4 a = ((const float4*)(abp0 + (size_t)(R0+rw)*128))[part];
    float4 b = ((const float4*)(abp1 + (size_t)(R0+rw)*128))[part];
    bf16x4 pk;
    pk[0] = (__bf16)(a.x + b.x); pk[1] = (__bf16)(a.y + b.y);
    pk[2] = (__bf16)(a.z + b.z); pk[3] = (__bf16)(a.w + b.w);
    *(bf16x4*)&Als[rw*136 + part*4] = pk;
  }
  __syncthreads();
  int wave = tid >> 6, lane = tid & 63, lm = lane & 31, lh = lane >> 5;
  bf16x8 bfr[8];
  const u16* wrow = wpT + (32*wave + lm)*128 + lh*8;
  #pragma unroll
  for (int ks = 0; ks < 8; ks++) bfr[ks] = *(const bf16x8*)(wrow + ks*16);
  f32x16 acc;
  #pragma unroll
  for (int r = 0; r < 16; r++) acc[r] = 0.f;
  #pragma unroll
  for (int ks = 0; ks < 8; ks++){
    bf16x8 a0 = *(const bf16x8*)&Als[lm*136 + ks*16 + lh*8];
    acc = mfma_bf16(a0, bfr[ks], acc);
  }
  float bias = bp[32*wave + lm];
  #pragma unroll
  for (int r = 0; r < 16; r++){
    int row0 = (r&3) + 8*(r>>2) + 4*lh;
    size_t f0 = (size_t)(R0 + row0)*128 + 32*wave + lm;
    out[f0] = acc[r] + bias + skip[f0];
  }
}

// ---------------------------------------------------------------- launch
extern "C" void kernel_launch(void* const* d_in, const int* in_sizes, int n_in,
                              void* d_out, int out_size, void* d_ws, size_t ws_size,
                              hipStream_t stream)
{
  const float* q    = (const float*)d_in[0];
  const float* k    = (const float*)d_in[1];
  const float* v    = (const float*)d_in[2];
  const float* skip = (const float*)d_in[3];
  const float* gq   = (const float*)d_in[4];
  const float* betq = (const float*)d_in[5];
  const float* gk   = (const float*)d_in[6];
  const float* betk = (const float*)d_in[7];
  const float* gv   = (const float*)d_in[8];
  const float* betv = (const float*)d_in[9];
  const float* wq   = (const float*)d_in[10];
  const float* bq   = (const float*)d_in[11];
  const float* wk   = (const float*)d_in[12];
  const float* bk   = (const float*)d_in[13];
  const float* wv   = (const float*)d_in[14];
  const float* bv   = (const float*)d_in[15];
  const float* wp   = (const float*)d_in[16];
  const float* bp   = (const float*)d_in[17];
  float* out = (float*)d_out;

  char* ws = (char*)d_ws;
  u16* wqT = (u16*)ws;                 // 16384 u16 each
  u16* wkT = wqT + 16384;
  u16* wvT = wkT + 16384;
  u16* wpT = wvT + 16384;
  float* bq2 = (float*)(ws + 131072);  // 128 f32 each
  float* bk2 = bq2 + 128;
  float* bv2 = bk2 + 128;
  float* uq2 = bv2 + 128;
  float* uk2 = uq2 + 128;
  float* uv2 = uk2 + 128;
  u16* qh = (u16*)(ws + 134144);       // [128][4][384][32] bf16 = 12.58 MB each
  u16* kh = qh + 6291456;
  u16* vh = kh + 6291456;
  float* abp0 = (float*)(ws + 37882880);   // [8192][128] f32 = 4 MB each
  float* abp1 = abp0 + 1048576;

  k_prep  <<<16,   512, 0, stream>>>(wq,bq,gq,betq, wk,bk,gk,betk, wv,bv,gv,betv, wp,
                                     wqT,wkT,wvT,wpT, bq2,bk2,bv2, uq2,uk2,uv2);
  k_lnproj<<<2304, 256, 0, stream>>>(q,k,v, wqT,wkT,wvT, bq2,bk2,bv2, uq2,uk2,uv2, qh,kh,vh);
  k_attn  <<<1024, 192, 0, stream>>>(qh,kh,vh, abp0,abp1);
  k_out   <<<256,  256, 0, stream>>>(abp0,abp1, wpT, bp, skip, out);
}

// Round 11
// 198.960 us; speedup vs baseline: 1.0906x; 1.0906x over previous
//
#include <hip/hip_runtime.h>

// CrossWinAttention on MI355X (gfx950), bf16 MFMA pipeline. R16:
//  - R15 postmortem: XCD pair-affinity fixed FETCH (30.8->18.7 MB) but wall
//    barely moved -> "wall=FETCH/rate" dead. Surviving model across R7-R15:
//    wall tracks BLOCK COUNT and co-residency, not bytes/waves: 512-blk ~50us,
//    1024-blk ~65us, and R9's forced sequential 256-blk batches ran ~26us per
//    batch (1 blk/CU) -> co-resident blocks contend on a per-CU resource.
//  - R16 tests that directly: k_attn grid 256 x 768 thr, ONE block per CU
//    (dynamic LDS 86KB request -> 2/CU impossible), each block runs TWO
//    (bl,h) tasks concurrently: waves 0-5 = task bid, waves 6-11 = bid+256,
//    each group with private V^T + abar_s in dynamic LDS. Per-wave code =
//    R7 verbatim (best-measured 48.1us). Same 512 tasks, same FETCH, same
//    12 waves/CU — only the block-sharing topology changes.
//    __launch_bounds__(768,3): cap ~170 VGPR, need ~90 (no R8 spill trap).
//  - k_prep (grid 16) / k_lnproj (R13b coalesced stores) / k_out (grid 256,
//    bf16 abar): best-known versions.
//  - Carried: S^T trick, V^T key-swizzle, LN folded into GEMM epilogue,
//    mean-over-N folded, scale*log2e folded into wq/bq (exp2-only softmax),
//    serial-sle softmax, hw bf16 cvt.

typedef unsigned short u16;
typedef __bf16 bf16x8 __attribute__((ext_vector_type(8)));
typedef __bf16 bf16x4 __attribute__((ext_vector_type(4)));
typedef float  f32x16 __attribute__((ext_vector_type(16)));
typedef unsigned short u16x8 __attribute__((ext_vector_type(8)));
typedef unsigned short u16x4 __attribute__((ext_vector_type(4)));

union U8 { u16x8 u; bf16x8 b; u16x4 h[2]; };

#if __has_builtin(__builtin_amdgcn_exp2f)
#define EXP2(x) __builtin_amdgcn_exp2f(x)
#else
#define EXP2(x) exp2f(x)
#endif

__device__ __forceinline__ f32x16 mfma_bf16(bf16x8 a, bf16x8 b, f32x16 c){
  return __builtin_amdgcn_mfma_f32_32x32x16_bf16(a, b, c, 0, 0, 0);
}

// 32x32x16 bf16 fragment conventions:
//  A: m=lane&31, k=(lane>>5)*8+j ; B: n=lane&31, k=(lane>>5)*8+j
//  C/D: col=lane&31, row=(reg&3)+8*(reg>>2)+4*(lane>>5)   [verified m74/m101]
// S^T = mfma(K, Q): col = q (fixed per lane), reg axis = keys. V^T stored with
// matching key swizzle so PV B-fragments are single 16B reads.

// ---------------------------------------------------------------- k_prep
// grid 16 = 4 weights x 4 col-chunks; 512 thr.
__global__ __launch_bounds__(512) void k_prep(
    const float* __restrict__ wq, const float* __restrict__ bq,
    const float* __restrict__ gq, const float* __restrict__ betq,
    const float* __restrict__ wk, const float* __restrict__ bk,
    const float* __restrict__ gk, const float* __restrict__ betk,
    const float* __restrict__ wv, const float* __restrict__ bv,
    const float* __restrict__ gv, const float* __restrict__ betv,
    const float* __restrict__ wp,
    u16* __restrict__ wqT, u16* __restrict__ wkT, u16* __restrict__ wvT, u16* __restrict__ wpT,
    float* __restrict__ bq2, float* __restrict__ bk2, float* __restrict__ bv2,
    float* __restrict__ uq2, float* __restrict__ uk2, float* __restrict__ uv2)
{
  __shared__ float wls[128*33];
  __shared__ float gls[128], bls[128];
  __shared__ float redb[128], redu[128];
  const float ALPHA_Q = 0.17677669529663687f * 1.4426950408889634f; // DH^-0.5 * log2(e)
  int bid = blockIdx.x, tid = threadIdx.x;
  int wsel = bid >> 2, chunk = bid & 3;
  const float *w, *bb, *g, *bet; u16* wT; float *b2, *u2; float alpha;
  if (wsel == 0){ w=wq; bb=bq; g=gq; bet=betq; wT=wqT; b2=bq2; u2=uq2; alpha=ALPHA_Q; }
  else if (wsel == 1){ w=wk; bb=bk; g=gk; bet=betk; wT=wkT; b2=bk2; u2=uk2; alpha=1.f; }
  else if (wsel == 2){ w=wv; bb=bv; g=gv; bet=betv; wT=wvT; b2=bv2; u2=uv2; alpha=1.f; }
  else { w=wp; bb=nullptr; g=nullptr; bet=nullptr; wT=wpT; b2=nullptr; u2=nullptr; alpha=1.f; }

  if (tid < 128){
    gls[tid] = g ? g[tid] : 1.f;
    bls[tid] = bet ? bet[tid] : 0.f;
  }
  const float4* w4 = (const float4*)w;
  #pragma unroll
  for (int i = 0; i < 2; i++){
    int idx = tid + i*512;
    int row = idx >> 3, f4c = idx & 7;
    float4 x = w4[row*32 + chunk*8 + f4c];
    wls[row*33 + f4c*4 + 0] = x.x;
    wls[row*33 + f4c*4 + 1] = x.y;
    wls[row*33 + f4c*4 + 2] = x.z;
    wls[row*33 + f4c*4 + 3] = x.w;
  }
  __syncthreads();
  if (tid < 128){
    int nl = tid >> 2, qp = tid & 3;
    float sb = 0.f, su = 0.f;
    alignas(16) __bf16 tmp[32];
    #pragma unroll
    for (int kk = 0; kk < 32; kk++){
      int k2 = qp*32 + kk;
      float wv_ = wls[k2*33 + nl];
      float gv_ = gls[k2];
      sb += bls[k2] * wv_;
      su += gv_ * wv_;
      tmp[kk] = (__bf16)(wv_ * gv_ * alpha);
    }
    int n = chunk*32 + nl;
    #pragma unroll
    for (int j = 0; j < 4; j++)
      *(bf16x8*)(wT + n*128 + qp*32 + j*8) = *(bf16x8*)&tmp[j*8];
    redb[tid] = sb; redu[tid] = su;
  }
  __syncthreads();
  if (tid < 128){
    int nl = tid >> 2, qp = tid & 3;
    if (qp == 0 && bb){
      int n = chunk*32 + nl;
      float s = bb[n] + redb[tid] + redb[tid+1] + redb[tid+2] + redb[tid+3];
      float u = redu[tid] + redu[tid+1] + redu[tid+2] + redu[tid+3];
      b2[n] = s * alpha;
      u2[n] = u * alpha;
    }
  }
}

// ---------------------------------------------------------------- k_lnproj
// grid 2304 = 128 (b,l) * 6 (n) * 3 (q/k/v); 256 thr (4 waves).
// Raw-x bf16 GEMM; LN in epilogue; C staged via LDS for coalesced stores.
__global__ __launch_bounds__(256) void k_lnproj(
    const float* __restrict__ qg, const float* __restrict__ kg, const float* __restrict__ vg,
    const u16* __restrict__ wqT, const u16* __restrict__ wkT, const u16* __restrict__ wvT,
    const float* __restrict__ bq2, const float* __restrict__ bk2, const float* __restrict__ bv2,
    const float* __restrict__ uq2, const float* __restrict__ uk2, const float* __restrict__ uv2,
    u16* __restrict__ qh, u16* __restrict__ kh, u16* __restrict__ vh)
{
  __shared__ alignas(16) u16 Abf[64*136];
  __shared__ float s1s[64], s2s[64];     // rs / rm
  int bid = blockIdx.x, tid = threadIdx.x;
  int which = bid % 3;
  int t = bid / 3;
  int n = t % 6, bl = t / 6;
  const float* src; const u16* wT; const float *b2, *u2; u16* dstb;
  if (which == 0){ src=qg; wT=wqT; b2=bq2; u2=uq2; dstb=qh; }
  else if (which == 1){ src=kg; wT=wkT; b2=bk2; u2=uk2; dstb=kh; }
  else { src=vg; wT=wvT; b2=bv2; u2=uv2; dstb=vh; }
  int b = bl >> 6, l = bl & 63;
  const float4* s4 = (const float4*)(src + (size_t)((b*6 + n)*64 + l)*64*128);
  int row = tid >> 2, j = tid & 3;
  float s1 = 0.f, s2 = 0.f;
  #pragma unroll
  for (int i = 0; i < 8; i++){
    float4 xv = s4[row*32 + i*4 + j];
    s1 += xv.x + xv.y + xv.z + xv.w;
    s2 += xv.x*xv.x + xv.y*xv.y + xv.z*xv.z + xv.w*xv.w;
    bf16x4 pk;
    pk[0] = (__bf16)xv.x; pk[1] = (__bf16)xv.y;
    pk[2] = (__bf16)xv.z; pk[3] = (__bf16)xv.w;
    *(bf16x4*)&Abf[row*136 + (i*4 + j)*4] = pk;
  }
  s1 += __shfl_xor(s1, 1, 64); s1 += __shfl_xor(s1, 2, 64);
  s2 += __shfl_xor(s2, 1, 64); s2 += __shfl_xor(s2, 2, 64);
  if (j == 0){
    float m = s1 * (1.f/128.f);
    float r = rsqrtf(s2 * (1.f/128.f) - m*m + 1e-5f);
    s1s[row] = r;          // rs
    s2s[row] = r * m;      // rm
  }
  __syncthreads();
  int wave = tid >> 6, lane = tid & 63, lm = lane & 31, lh = lane >> 5;
  bf16x8 bfr[8];
  const u16* wrow = wT + (32*wave + lm)*128 + lh*8;
  #pragma unroll
  for (int ks = 0; ks < 8; ks++) bfr[ks] = *(const bf16x8*)(wrow + ks*16);
  f32x16 acc0, acc1;
  #pragma unroll
  for (int r = 0; r < 16; r++){ acc0[r]=0.f; acc1[r]=0.f; }
  #pragma unroll
  for (int ks = 0; ks < 8; ks++){
    bf16x8 a0 = *(const bf16x8*)&Abf[lm*136       + ks*16 + lh*8];
    bf16x8 a1 = *(const bf16x8*)&Abf[(32+lm)*136  + ks*16 + lh*8];
    acc0 = mfma_bf16(a0, bfr[ks], acc0);
    acc1 = mfma_bf16(a1, bfr[ks], acc1);
  }
  int col = 32*wave + lm;
  float u2c = u2[col], bc = b2[col];
  __syncthreads();                       // all waves done READING Abf
  #pragma unroll
  for (int r = 0; r < 16; r++){
    int row0 = (r&3) + 8*(r>>2) + 4*lh;
    float y0 = s1s[row0]     * acc0[r] - s2s[row0]     * u2c + bc;
    float y1 = s1s[row0+32]  * acc1[r] - s2s[row0+32]  * u2c + bc;
    *(__bf16*)&Abf[row0*136 + col]      = (__bf16)y0;
    *(__bf16*)&Abf[(32+row0)*136 + col] = (__bf16)y1;
  }
  __syncthreads();
  // coalesced store: 1024 u16x8 chunks = 4 colgroups x 64 rows x 4 parts
  #pragma unroll
  for (int i = 0; i < 4; i++){
    int c = tid + i*256;
    int grp = c >> 8, rw = (c >> 2) & 63, part = c & 3;
    u16x8 val = *(const u16x8*)&Abf[rw*136 + grp*32 + part*8];
    *(u16x8*)(dstb + ((size_t)(bl*4 + grp)*384 + n*64 + rw)*32 + part*8) = val;
  }
}

// ---------------------------------------------------------------- k_attn
// grid 256 x 768 thr (12 waves); dynamic LDS 86016 B -> 1 block/CU forced.
// Two concurrent tasks per block: waves 0-5 -> (bl,h) = bid, waves 6-11 ->
// bid+256. Each group has private V^T (stride 392) + abar_s in dyn LDS.
// Per-wave body = R7 verbatim (A/B dual chains, serial sle, K from global).
__global__ __launch_bounds__(768, 3) void k_attn(
    const u16* __restrict__ qh, const u16* __restrict__ kh, const u16* __restrict__ vh,
    u16* __restrict__ abar)
{
  extern __shared__ __align__(16) char smem[];
  int bid = blockIdx.x, tid = threadIdx.x;
  int wave = tid >> 6, lane = tid & 63, lm = lane & 31, lh = lane >> 5;
  int grp = (wave >= 6) ? 1 : 0;
  int n = wave - 6*grp;               // view within task
  int tl = tid - 384*grp;             // 0..383 within group
  int bh = bid + 256*grp;             // task id 0..511
  int h = bh & 3, bl = bh >> 2;

  u16*   vts    = (u16*)  (smem + grp*25088);           // [32][392]
  float* abar_s = (float*)(smem + 50176 + grp*8192);    // [64][32]

  const u16* qb = qh + (size_t)bh * 12288;
  const u16* kb = kh + (size_t)bh * 12288;
  const u16* vb = vh + (size_t)bh * 12288;

  // Q fragments: group A = q rows n*64+lm, group B = +32
  const u16* qbase = qb + (size_t)(n*64 + lm)*32 + lh*8;
  bf16x8 qfA0 = *(const bf16x8*)(qbase);
  bf16x8 qfA1 = *(const bf16x8*)(qbase + 16);
  bf16x8 qfB0 = *(const bf16x8*)(qbase + 32*32);
  bf16x8 qfB1 = *(const bf16x8*)(qbase + 32*32 + 16);

  // stage this task's V transposed + key-swizzled (a-group perm {0,2,1,3,4,6,5,7})
  #pragma unroll
  for (int i = 0; i < 4; i++){
    int c = tl + i*384;                // 1536 16B chunks per task
    int key = c >> 2, part = c & 3;
    int u = key & 31, tt = key >> 5;
    int a = u >> 2;
    int anew = (a & 4) | ((a & 1) << 1) | ((a >> 1) & 1);
    int pos = tt*32 + anew*4 + (u & 3);
    u16x8 vv = *(const u16x8*)(vb + key*32 + part*8);
    #pragma unroll
    for (int jj = 0; jj < 8; jj++) vts[(part*8 + jj)*392 + pos] = vv[jj];
  }
  for (int idx = tl; idx < 2048; idx += 384) abar_s[idx] = 0.f;
  __syncthreads();

  const u16* vrow = &vts[lm*392 + 8*lh];
  const u16* krow = kb + lm*32 + lh*8;

  f32x16 oA, oB;
  #pragma unroll
  for (int r = 0; r < 16; r++){ oA[r] = 0.f; oB[r] = 0.f; }
  float sleA = 0.f, sleB = 0.f;

  #pragma unroll
  for (int kt = 0; kt < 12; kt++){
    bf16x8 kf0 = *(const bf16x8*)(krow + kt*1024);
    bf16x8 kf1 = *(const bf16x8*)(krow + kt*1024 + 16);
    f32x16 sa, sb_;
    #pragma unroll
    for (int r = 0; r < 16; r++){ sa[r] = 0.f; sb_[r] = 0.f; }
    __builtin_amdgcn_s_setprio(1);
    sa  = mfma_bf16(kf0, qfA0, sa);      // two independent chains (A/B)
    sb_ = mfma_bf16(kf0, qfB0, sb_);
    sa  = mfma_bf16(kf1, qfA1, sa);
    sb_ = mfma_bf16(kf1, qfB1, sb_);
    __builtin_amdgcn_s_setprio(0);
    U8 v0, v1;
    v0.u = *(const u16x8*)(vrow + kt*32);
    v1.u = *(const u16x8*)(vrow + kt*32 + 16);
    U8 pA0, pA1, pB0, pB1;
    #pragma unroll
    for (int r = 0; r < 8; r++){
      float eA0 = EXP2(sa[r]);
      float eA1 = EXP2(sa[r+8]);
      float eB0 = EXP2(sb_[r]);
      float eB1 = EXP2(sb_[r+8]);
      sleA += eA0 + eA1;
      sleB += eB0 + eB1;
      pA0.b[r] = (__bf16)eA0;            // v_cvt_pk_bf16_f32 (RNE)
      pA1.b[r] = (__bf16)eA1;
      pB0.b[r] = (__bf16)eB0;
      pB1.b[r] = (__bf16)eB1;
    }
    __builtin_amdgcn_s_setprio(1);
    oA = mfma_bf16(pA0.b, v0.b, oA);
    oB = mfma_bf16(pB0.b, v0.b, oB);
    oA = mfma_bf16(pA1.b, v1.b, oA);
    oB = mfma_bf16(pB1.b, v1.b, oB);
    __builtin_amdgcn_s_setprio(0);
  }

  // row sums: combine lh halves, broadcast reciprocals (1/6 = mean over n)
  sleA += __shfl_xor(sleA, 32, 64);
  sleB += __shfl_xor(sleB, 32, 64);
  float invA = (1.f/6.f) / sleA;
  float invB = (1.f/6.f) / sleB;

  // o lane(lm,lh) reg r = O[q=(r&3)+8*(r>>2)+4*lh][dh=lm]; w12 = q (A), 32+q (B)
  #pragma unroll
  for (int r = 0; r < 16; r++){
    int q_l = (r&3) + 8*(r>>2) + 4*lh;
    float a = oA[r] * __shfl(invA, q_l, 64);
    float b = oB[r] * __shfl(invB, q_l, 64);
    atomicAdd(&abar_s[q_l*32 + lm], a);
    atomicAdd(&abar_s[(32 + q_l)*32 + lm], b);
  }
  __syncthreads();
  u16* ob = abar + (size_t)(bl*64)*128 + h*32;
  for (int idx = tl; idx < 2048; idx += 384){
    int w12 = idx >> 5, dh = idx & 31;
    *(__bf16*)&ob[(size_t)w12*128 + dh] = (__bf16)abar_s[idx];
  }
}

// ---------------------------------------------------------------- k_out
// grid 256 = 8192 rows / 32; 256 thr (4 waves); wave w owns cols [32w,32w+32).
__global__ __launch_bounds__(256) void k_out(
    const u16* __restrict__ abar, const u16* __restrict__ wpT,
    const float* __restrict__ bp, const float* __restrict__ skip,
    float* __restrict__ out)
{
  __shared__ alignas(16) u16 Als[32*136];
  int tid = threadIdx.x;
  int R0 = blockIdx.x * 32;
  #pragma unroll
  for (int i = 0; i < 2; i++){
    int c = tid + i*256;                 // 512 16B chunks: 32 rows x 16
    int row = c >> 4, part = c & 15;
    *(u16x8*)&Als[row*136 + part*8] = *(const u16x8*)(abar + (size_t)(R0+row)*128 + part*8);
  }
  __syncthreads();
  int wave = tid >> 6, lane = tid & 63, lm = lane & 31, lh = lane >> 5;
  bf16x8 bfr[8];
  const u16* wrow = wpT + (32*wave + lm)*128 + lh*8;
  #pragma unroll
  for (int ks = 0; ks < 8; ks++) bfr[ks] = *(const bf16x8*)(wrow + ks*16);
  f32x16 acc;
  #pragma unroll
  for (int r = 0; r < 16; r++) acc[r] = 0.f;
  #pragma unroll
  for (int ks = 0; ks < 8; ks++){
    bf16x8 a0 = *(const bf16x8*)&Als[lm*136 + ks*16 + lh*8];
    acc = mfma_bf16(a0, bfr[ks], acc);
  }
  float bias = bp[32*wave + lm];
  #pragma unroll
  for (int r = 0; r < 16; r++){
    int row0 = (r&3) + 8*(r>>2) + 4*lh;
    size_t f0 = (size_t)(R0 + row0)*128 + 32*wave + lm;
    out[f0] = acc[r] + bias + skip[f0];
  }
}

// ---------------------------------------------------------------- launch
extern "C" void kernel_launch(void* const* d_in, const int* in_sizes, int n_in,
                              void* d_out, int out_size, void* d_ws, size_t ws_size,
                              hipStream_t stream)
{
  const float* q    = (const float*)d_in[0];
  const float* k    = (const float*)d_in[1];
  const float* v    = (const float*)d_in[2];
  const float* skip = (const float*)d_in[3];
  const float* gq   = (const float*)d_in[4];
  const float* betq = (const float*)d_in[5];
  const float* gk   = (const float*)d_in[6];
  const float* betk = (const float*)d_in[7];
  const float* gv   = (const float*)d_in[8];
  const float* betv = (const float*)d_in[9];
  const float* wq   = (const float*)d_in[10];
  const float* bq   = (const float*)d_in[11];
  const float* wk   = (const float*)d_in[12];
  const float* bk   = (const float*)d_in[13];
  const float* wv   = (const float*)d_in[14];
  const float* bv   = (const float*)d_in[15];
  const float* wp   = (const float*)d_in[16];
  const float* bp   = (const float*)d_in[17];
  float* out = (float*)d_out;

  char* ws = (char*)d_ws;
  u16* wqT = (u16*)ws;                 // 16384 u16 each
  u16* wkT = wqT + 16384;
  u16* wvT = wkT + 16384;
  u16* wpT = wvT + 16384;
  float* bq2 = (float*)(ws + 131072);  // 128 f32 each
  float* bk2 = bq2 + 128;
  float* bv2 = bk2 + 128;
  float* uq2 = bv2 + 128;
  float* uk2 = uq2 + 128;
  float* uv2 = uk2 + 128;
  u16* qh = (u16*)(ws + 134144);       // [128][4][384][32] bf16 = 12.58 MB each
  u16* kh = qh + 6291456;
  u16* vh = kh + 6291456;
  u16* abar = vh + 6291456;            // [8192][128] bf16 = 2 MB

  k_prep  <<<16,   512, 0, stream>>>(wq,bq,gq,betq, wk,bk,gk,betk, wv,bv,gv,betv, wp,
                                     wqT,wkT,wvT,wpT, bq2,bk2,bv2, uq2,uk2,uv2);
  k_lnproj<<<2304, 256, 0, stream>>>(q,k,v, wqT,wkT,wvT, bq2,bk2,bv2, uq2,uk2,uv2, qh,kh,vh);
  k_attn  <<<256,  768, 86016, stream>>>(qh,kh,vh, abar);
  k_out   <<<256,  256, 0, stream>>>(abar, wpT, bp, skip, out);
}